// Round 3
// baseline (406.810 us; speedup 1.0000x reference)
//
#include <hip/hip_runtime.h>
#include <hip/hip_bf16.h>

typedef __bf16 bf16_t;
typedef bf16_t bf16x8 __attribute__((ext_vector_type(8)));
typedef float f32x4 __attribute__((ext_vector_type(4)));
typedef unsigned short u16;
typedef unsigned int u32;

static constexpr int kHW = 192 * 320;          // 61440
static constexpr float kC = 4.77464829275686f; // 30 / (2*pi)

// round-to-nearest-even f32 -> bf16
__device__ __forceinline__ u16 f2bf(float f) {
  u32 u = __float_as_uint(f);
  return (u16)((u + 0x7FFFu + ((u >> 16) & 1u)) >> 16);
}

__device__ __forceinline__ u32 pack2(float a, float b) {
  __hip_bfloat162 h = __float22bfloat162_rn(make_float2(a, b));
  union { __hip_bfloat162 h2; u32 u; } cv;
  cv.h2 = h;
  return cv.u;
}

// bf16 weight workspace layout (element offsets). W0..W4 pre-scaled by kC.
static constexpr int OFF_W0 = 0;        // [64][64] (t-column folded into bias)
static constexpr int OFF_W1 = 4096;     // [64][64]
static constexpr int OFF_W2 = 8192;     // [256][64]
static constexpr int OFF_W3 = 24576;    // [256][256]
static constexpr int OFF_W4 = 90112;    // [256][256]
static constexpr int OFF_W5 = 155648;   // [64][256] (NOT scaled)
static constexpr int W_TOTAL = 172032;  // u16 elements
// fp32 bias block after weights (float offsets in bws):
// cb0[64]@0, cw64[64]@64, cb1[64]@128, cb2[256]@192, cb3[256]@448,
// cb4[256]@704, b5[64]@960 -> 1024 floats. cb*/cw64 pre-scaled by kC.
static constexpr int B_TOTAL = 1024;

__global__ void convert_weights(const float* __restrict__ w0, const float* __restrict__ w1,
                                const float* __restrict__ w2, const float* __restrict__ w3,
                                const float* __restrict__ w4, const float* __restrict__ w5,
                                const float* __restrict__ b0, const float* __restrict__ b1,
                                const float* __restrict__ b2, const float* __restrict__ b3,
                                const float* __restrict__ b4, const float* __restrict__ b5,
                                u16* __restrict__ wb, float* __restrict__ bws) {
  int i = blockIdx.x * 256 + threadIdx.x;
  if (i < W_TOTAL) {
    float v, s = kC;
    if (i < OFF_W1)      { int o = i >> 6, k = i & 63; v = w0[o * 65 + k]; }
    else if (i < OFF_W2) { v = w1[i - OFF_W1]; }
    else if (i < OFF_W3) { v = w2[i - OFF_W2]; }
    else if (i < OFF_W4) { v = w3[i - OFF_W3]; }
    else if (i < OFF_W5) { v = w4[i - OFF_W4]; }
    else                 { v = w5[i - OFF_W5]; s = 1.0f; }
    wb[i] = f2bf(v * s);
  } else {
    int j = i - W_TOTAL;  // 0..1023
    float v;
    if (j < 64)       v = kC * b0[j];
    else if (j < 128) v = kC * w0[(j - 64) * 65 + 64];
    else if (j < 192) v = kC * b1[j - 128];
    else if (j < 448) v = kC * b2[j - 192];
    else if (j < 704) v = kC * b3[j - 448];
    else if (j < 960) v = kC * b4[j - 704];
    else              v = b5[j - 960];
    bws[j] = v;
  }
}

// Epilogue for one 16x16 C-tile (non-last layers): act = sin(2*pi*frac(acc)).
__device__ __forceinline__ void epilogue_sin(f32x4 acc, u16* act_out, int p, int g,
                                             int quad, int sw) {
  float s0 = __builtin_amdgcn_sinf(__builtin_amdgcn_fractf(acc[0]));
  float s1 = __builtin_amdgcn_sinf(__builtin_amdgcn_fractf(acc[1]));
  float s2 = __builtin_amdgcn_sinf(__builtin_amdgcn_fractf(acc[2]));
  float s3 = __builtin_amdgcn_sinf(__builtin_amdgcn_fractf(acc[3]));
  uint2 v;
  v.x = pack2(s0, s1);
  v.y = pack2(s2, s3);
  *reinterpret_cast<uint2*>(act_out + p * 256 + ((g ^ sw) * 8) + (quad & 1) * 4) = v;
}

// One layer: D[o][p] = sum_k W[o][k]*act[p][k] + bias.
// ks-outer, 2*NOT independent accumulator chains (2 p-tiles in flight).
template<int K, int NOT, int NPAIR, bool LAST>
__device__ __forceinline__ void layer_fn(const u16* __restrict__ wb, const float* bias,
                                         const u16* act_in, u16* act_out,
                                         float* __restrict__ out_base,
                                         int o_tile0, int pair0, int lane) {
  constexpr int KT = K / 32;
  const int l15  = lane & 15;
  const int quad = lane >> 4;
  const int sw   = l15 & 7;

  // weight frags, ks-major load order so the first MFMA depends on the oldest loads
  bf16x8 wf[NOT][KT];
#pragma unroll
  for (int ks = 0; ks < KT; ++ks)
#pragma unroll
    for (int ot = 0; ot < NOT; ++ot)
      wf[ot][ks] = *reinterpret_cast<const bf16x8*>(
          wb + ((o_tile0 + ot) * 16 + l15) * K + ks * 32 + quad * 8);

  f32x4 bv[NOT];
#pragma unroll
  for (int ot = 0; ot < NOT; ++ot)
    bv[ot] = *reinterpret_cast<const f32x4*>(bias + (o_tile0 + ot) * 16 + quad * 4);

#pragma unroll 1
  for (int pr = 0; pr < NPAIR; ++pr) {
    const int p0 = ((pair0 + pr) * 2 + 0) * 16 + l15;
    const int p1 = ((pair0 + pr) * 2 + 1) * 16 + l15;
    f32x4 acc[2][NOT];
#pragma unroll
    for (int ot = 0; ot < NOT; ++ot) { acc[0][ot] = bv[ot]; acc[1][ot] = bv[ot]; }

#pragma unroll
    for (int ks = 0; ks < KT; ++ks) {
      const int off = ((ks * 4 + quad) ^ sw) * 8;
      bf16x8 a0 = *reinterpret_cast<const bf16x8*>(act_in + p0 * 256 + off);
      bf16x8 a1 = *reinterpret_cast<const bf16x8*>(act_in + p1 * 256 + off);
#pragma unroll
      for (int ot = 0; ot < NOT; ++ot) {
        acc[0][ot] = __builtin_amdgcn_mfma_f32_16x16x32_bf16(wf[ot][ks], a0, acc[0][ot], 0, 0, 0);
        acc[1][ot] = __builtin_amdgcn_mfma_f32_16x16x32_bf16(wf[ot][ks], a1, acc[1][ot], 0, 0, 0);
      }
    }

#pragma unroll
    for (int h = 0; h < 2; ++h) {
      const int p = h ? p1 : p0;
#pragma unroll
      for (int ot = 0; ot < NOT; ++ot) {
        if constexpr (LAST) {
          const int o = (o_tile0 + ot) * 16 + quad * 4;
          float* dst = out_base + (size_t)o * kHW + p;
#pragma unroll
          for (int r = 0; r < 4; ++r) dst[(size_t)r * kHW] = acc[h][ot][r];
        } else {
          epilogue_sin(acc[h][ot], act_out, p, (o_tile0 + ot) * 2 + (quad >> 1), quad, sw);
        }
      }
    }
  }
}

__global__ void __launch_bounds__(512, 4)
siren_main(const float* __restrict__ feat, const float* __restrict__ times,
           const u16* __restrict__ wb, const float* __restrict__ bws,
           float* __restrict__ out) {
  __shared__ __align__(16) u16 actA[64 * 256];
  __shared__ __align__(16) u16 actB[64 * 256];
  __shared__ __align__(16) float bias_lds[960];

  const int tid = threadIdx.x;
  const int bid = blockIdx.x;
  const int c   = bid / 1920;
  const int pb  = bid % 1920;
  const int p0g = pb * 64;
  const int bq  = p0g / kHW;
  const int hw0 = p0g % kHW;
  const float t = times[c];

  const int wave = tid >> 6;
  const int lane = tid & 63;
  const int l15  = lane & 15;
  const int quad = lane >> 4;
  const int sw   = l15 & 7;

  // ---- preload L0 weights + bias into registers (overlaps feat staging) ----
  bf16x8 wf0[2];
  f32x4  bv0;
  {
    const int o = (wave & 3) * 16 + l15;
    wf0[0] = *reinterpret_cast<const bf16x8*>(wb + OFF_W0 + o * 64 + quad * 8);
    wf0[1] = *reinterpret_cast<const bf16x8*>(wb + OFF_W0 + o * 64 + 32 + quad * 8);
    const int ob = (wave & 3) * 16 + quad * 4;
    f32x4 cb = *reinterpret_cast<const f32x4*>(bws + ob);
    f32x4 cw = *reinterpret_cast<const f32x4*>(bws + 64 + ob);
#pragma unroll
    for (int r = 0; r < 4; ++r) bv0[r] = cb[r] + t * cw[r];
  }

  // bias staging for layers 1..5
  for (int i = tid; i < 832; i += 512) bias_lds[128 + i] = bws[192 + i];
  if (tid < 64) bias_lds[64 + tid] = bws[128 + tid];

  // input staging: act[p][ch] = bf16(feat[bq][ch][hw0+p]), swizzled, one b128/thread
  {
    const float* fbase = feat + (size_t)bq * 64 * kHW + hw0;
    const int p = tid & 63;
    const int g = tid >> 6;  // channel granule 0..7
    float v[8];
#pragma unroll
    for (int j = 0; j < 8; ++j) v[j] = fbase[(size_t)(g * 8 + j) * kHW + p];
    uint4 pk;
    pk.x = pack2(v[0], v[1]);
    pk.y = pack2(v[2], v[3]);
    pk.z = pack2(v[4], v[5]);
    pk.w = pack2(v[6], v[7]);
    *reinterpret_cast<uint4*>(actA + p * 256 + ((g ^ (p & 7)) * 8)) = pk;
  }
  __syncthreads();

  float* out_base = out + (size_t)(c * 2 + bq) * 64 * kHW + hw0;

  // ---- L0 (preloaded weights): NOT=1, KT=2, one p-pair per wave ----
  {
    const int pp = wave >> 2;
    const int pA = (pp * 2 + 0) * 16 + l15;
    const int pB = (pp * 2 + 1) * 16 + l15;
    f32x4 acc0 = bv0, acc1 = bv0;
#pragma unroll
    for (int ks = 0; ks < 2; ++ks) {
      const int off = ((ks * 4 + quad) ^ sw) * 8;
      bf16x8 a0 = *reinterpret_cast<const bf16x8*>(actA + pA * 256 + off);
      bf16x8 a1 = *reinterpret_cast<const bf16x8*>(actA + pB * 256 + off);
      acc0 = __builtin_amdgcn_mfma_f32_16x16x32_bf16(wf0[ks], a0, acc0, 0, 0, 0);
      acc1 = __builtin_amdgcn_mfma_f32_16x16x32_bf16(wf0[ks], a1, acc1, 0, 0, 0);
    }
    const int g = (wave & 3) * 2 + (quad >> 1);
    epilogue_sin(acc0, actB, pA, g, quad, sw);
    epilogue_sin(acc1, actB, pB, g, quad, sw);
  }
  __syncthreads();
  layer_fn<64, 1, 1, false>(wb + OFF_W1, bias_lds + 64, actB, actA, nullptr,
                            wave & 3, wave >> 2, lane);
  __syncthreads();
  layer_fn<64, 2, 2, false>(wb + OFF_W2, bias_lds + 128, actA, actB, nullptr,
                            wave * 2, 0, lane);
  __syncthreads();
  layer_fn<256, 2, 2, false>(wb + OFF_W3, bias_lds + 384, actB, actA, nullptr,
                             wave * 2, 0, lane);
  __syncthreads();
  layer_fn<256, 2, 2, false>(wb + OFF_W4, bias_lds + 640, actA, actB, nullptr,
                             wave * 2, 0, lane);
  __syncthreads();
  layer_fn<256, 1, 1, true>(wb + OFF_W5, bias_lds + 896, actB, nullptr, out_base,
                            wave & 3, wave >> 2, lane);
}

extern "C" void kernel_launch(void* const* d_in, const int* in_sizes, int n_in,
                              void* d_out, int out_size, void* d_ws, size_t ws_size,
                              hipStream_t stream) {
  const float* feat  = (const float*)d_in[0];
  const float* times = (const float*)d_in[1];
  const float* w0 = (const float*)d_in[2];
  const float* b0 = (const float*)d_in[3];
  const float* w1 = (const float*)d_in[4];
  const float* b1 = (const float*)d_in[5];
  const float* w2 = (const float*)d_in[6];
  const float* b2 = (const float*)d_in[7];
  const float* w3 = (const float*)d_in[8];
  const float* b3 = (const float*)d_in[9];
  const float* w4 = (const float*)d_in[10];
  const float* b4 = (const float*)d_in[11];
  const float* w5 = (const float*)d_in[12];
  const float* b5 = (const float*)d_in[13];
  u16*   wb  = (u16*)d_ws;
  float* bws = (float*)((char*)d_ws + (size_t)W_TOTAL * 2);
  float* out = (float*)d_out;

  convert_weights<<<(W_TOTAL + B_TOTAL) / 256, 256, 0, stream>>>(
      w0, w1, w2, w3, w4, w5, b0, b1, b2, b3, b4, b5, wb, bws);
  siren_main<<<5760, 512, 0, stream>>>(feat, times, wb, bws, out);
}